// Round 8
// baseline (475.417 us; speedup 1.0000x reference)
//
#include <hip/hip_runtime.h>
#include <stdint.h>
#include <stddef.h>

// ============================================================================
// RegionAttn fused pipeline v8.
//  - gemm_pw: persistent-weight GEMM for K=256 (QKV + FFN-w1): W in LDS once,
//    A register-streamed, barrier-free grid-strided M-loop.
//  - attn19 v5: 608-thread d-quarter split (9.5 waves/block).
//  - gemm_ln v2 (out-projs + FFN-w2, K=1024) unchanged (verified).
//
// Workspace map (MB offsets, sizes exact):
//   WT    @0   (2)    bf16 weights [n][k], whole run
//   FE    @2   (8)    pool output [B,4,256]
//   QKV4  @10  (24)   [B*4, 768]
//   CTX4  @34  (8)
//   REF   @42  (8)    LN(ctx4@wo + fe)  [B,4,256]
//   X2    @50  (38)   x + ref[rid]      [B*19,256]
//   QKV19 @88  (114)  [B*19, 768]       dead after attn19
//   CTX19 @202 (38)                     dead after lsa out-proj
//   FUSED @88  (38)   alias QKV19 head
//   H     @126 (76)   alias QKV19 tail  (per FFN half)
// Peak 240 MB.
// ============================================================================

#define DEVINL __device__ __forceinline__

typedef __attribute__((ext_vector_type(8))) short short8;
typedef __attribute__((ext_vector_type(4))) float floatx4;
typedef __attribute__((ext_vector_type(8))) unsigned short ushort8;
typedef __attribute__((ext_vector_type(4))) unsigned short ushort4v;

DEVINL float bf2f(unsigned short u){
  union { unsigned int i; float f; } x; x.i = ((unsigned int)u) << 16; return x.f;
}
DEVINL unsigned short f2bf(float f){
  union { float f; unsigned int i; } x; x.f = f;
  unsigned int r = x.i + 0x7fffu + ((x.i >> 16) & 1u);   // RNE
  return (unsigned short)(r >> 16);
}

typedef __attribute__((address_space(1))) void gvoid_t;
typedef __attribute__((address_space(3))) void lvoid_t;
DEVINL void gload_lds16(const void* g, void* l){
  __builtin_amdgcn_global_load_lds((gvoid_t*)g, (lvoid_t*)l, 16, 0, 0);
}

// ---------------------------------------------------------------------------
// Weight prep: fp32 [K][N] -> bf16 transposed [N][K].
// ---------------------------------------------------------------------------
__global__ __launch_bounds__(256) void wprep_all(
    const float* __restrict__ rq, const float* __restrict__ rk,
    const float* __restrict__ rv, const float* __restrict__ ro,
    const float* __restrict__ lq, const float* __restrict__ lk,
    const float* __restrict__ lv, const float* __restrict__ lo,
    const float* __restrict__ w1, const float* __restrict__ w2,
    unsigned short* __restrict__ wt)
{
  int idx = blockIdx.x * 256 + threadIdx.x;      // 0 .. 1048575
  const float* W; unsigned short* D; int N, r;
  const int K = (idx < 786432) ? 256 : 1024;
  if (idx < 524288){
    int wsel = idx >> 16; r = idx & 65535; N = 256; D = wt + wsel * 65536;
    switch (wsel){
      case 0: W = rq; break; case 1: W = rk; break; case 2: W = rv; break; case 3: W = ro; break;
      case 4: W = lq; break; case 5: W = lk; break; case 6: W = lv; break; default: W = lo; break;
    }
  } else if (idx < 786432){
    r = idx - 524288; N = 1024; D = wt + 524288; W = w1;
  } else {
    r = idx - 786432; N = 256; D = wt + 786432; W = w2;
  }
  int k = r / N, n = r - k * N;
  D[(size_t)n * K + k] = f2bf(W[r]);
}

// ---------------------------------------------------------------------------
// Region avg-pool: x fp32 [B,19,256] -> fe bf16 [B,4,256]
// ---------------------------------------------------------------------------
__global__ __launch_bounds__(256) void pool_kernel(const float* __restrict__ x,
                                                   unsigned short* __restrict__ fe)
{
  const int b = blockIdx.x, d = threadIdx.x;
  const float* xb = x + (size_t)b * 4864 + d;
  float s0 = xb[0*256]+xb[1*256]+xb[5*256]+xb[8*256]+xb[9*256]+xb[10*256]+xb[14*256];
  float s1 = xb[2*256]+xb[11*256]+xb[17*256];
  float s2 = xb[3*256]+xb[12*256]+xb[18*256];
  float s3 = xb[4*256]+xb[6*256]+xb[7*256]+xb[13*256]+xb[15*256]+xb[16*256];
  unsigned short* fb = fe + (size_t)b * 1024 + d;
  fb[0]   = f2bf(s0 * (1.f/7.f));
  fb[256] = f2bf(s1 * (1.f/3.f));
  fb[512] = f2bf(s2 * (1.f/3.f));
  fb[768] = f2bf(s3 * (1.f/6.f));
}

// ---------------------------------------------------------------------------
// gemm_pw: persistent-weight GEMM, K == 256 ONLY.
// C[M,N] = act(A[M,K] @ Bt[N,K]^T). Block: 4 waves (2x2), BN=128 col-panel
// fixed by blockIdx.y; W-panel (128x256 bf16 = 64KB, 4 swizzled BK=64 panels)
// staged to LDS ONCE; then grid-strided M-loop with NO barriers:
// a-frags global->VGPR (16B/lane), b-frags from static LDS.
// ---------------------------------------------------------------------------
template<int RELU>
__global__ __launch_bounds__(256, 2)
void gemm_pw_kernel(const unsigned short* __restrict__ A,
                    const unsigned short* __restrict__ Bt,
                    unsigned short* __restrict__ C,
                    int N, int mtiles)
{
  __shared__ __align__(1024) unsigned short Wl[4][8192];   // 4 panels x 16KB
  const int tid  = threadIdx.x;
  const int wave = tid >> 6, lane = tid & 63;
  const int wm = wave >> 1, wn = wave & 1;
  const int rowB0 = blockIdx.y * 128;
  const int stg_row = lane >> 3;
  const int stg_kb  = (((lane & 7) ^ (lane >> 3)) << 4);
  const int K = 256;

  // stage W once: 64 chunks of 1KB (panel p = k-block, row-group g)
  #pragma unroll
  for (int s = 0; s < 16; ++s){
    int c = wave * 16 + s;
    int p = c >> 4;                 // 0..3
    int g = c & 15;                 // 0..15
    int r = g * 8 + stg_row;
    gload_lds16((const char*)(Bt + (size_t)(rowB0 + r) * K) + p * 128 + stg_kb,
                (char*)(&Wl[p][0]) + g * 1024);
  }
  __syncthreads();

  const int aro = wm * 64 + (lane & 15);      // A row offset within tile
  const int ako = (lane >> 4) << 3;           // A k offset (elements)

  for (int mt = blockIdx.x; mt < mtiles; mt += gridDim.x){
    const int rowA0 = mt * 128;
    floatx4 acc[4][4];
    #pragma unroll
    for (int i = 0; i < 4; ++i)
      #pragma unroll
      for (int j = 0; j < 4; ++j) acc[i][j] = (floatx4){0.f, 0.f, 0.f, 0.f};

    #pragma unroll
    for (int kk = 0; kk < 8; ++kk){
      const char* Bs = (const char*)(&Wl[kk >> 1][0]);
      short8 a[4], b[4];
      #pragma unroll
      for (int i = 0; i < 4; ++i)
        a[i] = *(const short8*)(A + (size_t)(rowA0 + aro + i * 16) * K + kk * 32 + ako);
      #pragma unroll
      for (int j = 0; j < 4; ++j){
        int row = wn * 64 + j * 16 + (lane & 15);
        int kb  = (((kk & 1) << 6) + ((lane >> 4) << 4)) ^ ((row & 7) << 4);
        b[j] = *(const short8*)(Bs + row * 128 + kb);
      }
      #pragma unroll
      for (int i = 0; i < 4; ++i)
        #pragma unroll
        for (int j = 0; j < 4; ++j)
          acc[i][j] = __builtin_amdgcn_mfma_f32_16x16x32_bf16(a[i], b[j], acc[i][j], 0, 0, 0);
    }

    const int cr = (lane >> 4) << 2;
    const int cc = lane & 15;
    #pragma unroll
    for (int i = 0; i < 4; ++i){
      #pragma unroll
      for (int j = 0; j < 4; ++j){
        int r0 = rowA0 + wm * 64 + i * 16 + cr;
        int c0 = rowB0 + wn * 64 + j * 16 + cc;
        #pragma unroll
        for (int r = 0; r < 4; ++r){
          float v = acc[i][j][r];
          if (RELU) v = fmaxf(v, 0.f);
          C[(size_t)(r0 + r) * N + c0] = f2bf(v);
        }
      }
    }
  }
}

// ---------------------------------------------------------------------------
// gemm_ln v2: Out[M,256] = LN(A[M,K] @ Bt[256,K]^T + Res[M,256]).
// BM=64, BN=256, BK=64, 512 thr (8 waves 2x4). (verified; unchanged)
// ---------------------------------------------------------------------------
template<int OUTF32>
__global__ __launch_bounds__(512, 4)
void gemm_ln_kernel(const unsigned short* __restrict__ A,
                    const unsigned short* __restrict__ Bt,
                    const unsigned short* __restrict__ Res,
                    void* __restrict__ Out, int M, int K)
{
  __shared__ __align__(1024) char lds[2][40960];   // A@0 (8KB), B@8192 (32KB)
  const int tid  = threadIdx.x;
  const int wave = tid >> 6, lane = tid & 63;
  const int wm = wave >> 2, wn = wave & 3;
  const int rowA0 = blockIdx.x * 64;
  const int stg_row = lane >> 3;
  const int stg_kb  = (((lane & 7) ^ (lane >> 3)) << 4);

  floatx4 acc[2][4];
  #pragma unroll
  for (int i = 0; i < 2; ++i)
    #pragma unroll
    for (int j = 0; j < 4; ++j) acc[i][j] = (floatx4){0.f, 0.f, 0.f, 0.f};

  const int nk = K >> 6;
  int cur = 0;
  #pragma unroll
  for (int s = 0; s < 5; ++s){
    int chunk = wave * 5 + s;
    const unsigned short* src = (chunk < 8)
      ? A  + (size_t)(rowA0 + chunk * 8 + stg_row) * K
      : Bt + (size_t)((chunk - 8) * 8 + stg_row) * K;
    gload_lds16((const char*)src + stg_kb, &lds[0][0] + chunk * 1024);
  }
  __syncthreads();

  for (int kt = 0; kt < nk; ++kt){
    if (kt + 1 < nk){
      const int kbase = (kt + 1) << 7;
      #pragma unroll
      for (int s = 0; s < 5; ++s){
        int chunk = wave * 5 + s;
        const unsigned short* src = (chunk < 8)
          ? A  + (size_t)(rowA0 + chunk * 8 + stg_row) * K
          : Bt + (size_t)((chunk - 8) * 8 + stg_row) * K;
        gload_lds16((const char*)src + kbase + stg_kb, &lds[cur ^ 1][0] + chunk * 1024);
      }
    }
    const char* As = &lds[cur][0];
    const char* Bs = &lds[cur][0] + 8192;
    #pragma unroll
    for (int kk = 0; kk < 2; ++kk){
      short8 a[2], b[4];
      #pragma unroll
      for (int i = 0; i < 2; ++i){
        int row = wm * 32 + i * 16 + (lane & 15);
        int kb  = (kk * 64 + ((lane >> 4) << 4)) ^ ((row & 7) << 4);
        a[i] = *(const short8*)(As + row * 128 + kb);
      }
      #pragma unroll
      for (int j = 0; j < 4; ++j){
        int row = wn * 64 + j * 16 + (lane & 15);
        int kb  = (kk * 64 + ((lane >> 4) << 4)) ^ ((row & 7) << 4);
        b[j] = *(const short8*)(Bs + row * 128 + kb);
      }
      #pragma unroll
      for (int i = 0; i < 2; ++i)
        #pragma unroll
        for (int j = 0; j < 4; ++j)
          acc[i][j] = __builtin_amdgcn_mfma_f32_16x16x32_bf16(a[i], b[j], acc[i][j], 0, 0, 0);
    }
    __syncthreads();
    cur ^= 1;
  }

  float* red_s = (float*)&lds[0][0];     // [4][64]
  float* red_q = red_s + 256;            // [4][64]
  float* mu_a  = red_s + 512;            // [64]
  float* rs_a  = red_s + 576;            // [64]
  const int g  = lane >> 4;
  const int cl = lane & 15;
  #pragma unroll
  for (int i = 0; i < 2; ++i){
    #pragma unroll
    for (int r = 0; r < 4; ++r){
      const int rowl = wm * 32 + i * 16 + g * 4 + r;
      float s = 0.f, q = 0.f;
      #pragma unroll
      for (int j = 0; j < 4; ++j){
        float v = acc[i][j][r] +
                  bf2f(Res[(size_t)(rowA0 + rowl) * 256 + wn * 64 + j * 16 + cl]);
        acc[i][j][r] = v;
        s += v; q += v * v;
      }
      #pragma unroll
      for (int off = 1; off < 16; off <<= 1){
        s += __shfl_xor(s, off); q += __shfl_xor(q, off);
      }
      if (cl == 0){ red_s[wn * 64 + rowl] = s; red_q[wn * 64 + rowl] = q; }
    }
  }
  __syncthreads();
  if (tid < 64){
    float S = red_s[tid] + red_s[64 + tid] + red_s[128 + tid] + red_s[192 + tid];
    float Q = red_q[tid] + red_q[64 + tid] + red_q[128 + tid] + red_q[192 + tid];
    float mu = S * (1.f / 256.f);
    float var = Q * (1.f / 256.f) - mu * mu;
    mu_a[tid] = mu;
    rs_a[tid] = rsqrtf(var + 1e-5f);
  }
  __syncthreads();
  #pragma unroll
  for (int i = 0; i < 2; ++i){
    #pragma unroll
    for (int r = 0; r < 4; ++r){
      const int rowl = wm * 32 + i * 16 + g * 4 + r;
      const float mu = mu_a[rowl], rs = rs_a[rowl];
      #pragma unroll
      for (int j = 0; j < 4; ++j){
        float w = (acc[i][j][r] - mu) * rs;
        size_t idx = (size_t)(rowA0 + rowl) * 256 + wn * 64 + j * 16 + cl;
        if (OUTF32) ((float*)Out)[idx] = w;
        else        ((unsigned short*)Out)[idx] = f2bf(w);
      }
    }
  }
}

// ---------------------------------------------------------------------------
// rsa attention: 4 tokens, 8 heads, QKV concat rows [B*4][768].
// ---------------------------------------------------------------------------
__global__ __launch_bounds__(256) void attn4_kernel(
    const unsigned short* __restrict__ QKV, unsigned short* __restrict__ ctx)
{
  const int t = threadIdx.x;
  const int lb = t >> 5, u = t & 31, h = u >> 2, q = u & 3;
  const size_t b = (size_t)blockIdx.x * 8 + lb;
  const unsigned short* tb = QKV + b * 4 * 768;

  float qf[32];
  {
    const ushort8* qp = (const ushort8*)(tb + (size_t)q * 768 + h * 32);
    #pragma unroll
    for (int g = 0; g < 4; ++g){
      ushort8 v = qp[g];
      #pragma unroll
      for (int e = 0; e < 8; ++e) qf[g * 8 + e] = bf2f(v[e]);
    }
  }
  float sc[4];
  #pragma unroll
  for (int s = 0; s < 4; ++s){
    const ushort8* kp = (const ushort8*)(tb + (size_t)s * 768 + 256 + h * 32);
    float a0 = 0, a1 = 0, a2 = 0, a3 = 0;
    #pragma unroll
    for (int g = 0; g < 4; ++g){
      ushort8 v = kp[g];
      a0 += qf[g*8+0]*bf2f(v[0]); a1 += qf[g*8+1]*bf2f(v[1]);
      a2 += qf[g*8+2]*bf2f(v[2]); a3 += qf[g*8+3]*bf2f(v[3]);
      a0 += qf[g*8+4]*bf2f(v[4]); a1 += qf[g*8+5]*bf2f(v[5]);
      a2 += qf[g*8+6]*bf2f(v[6]); a3 += qf[g*8+7]*bf2f(v[7]);
    }
    sc[s] = ((a0 + a1) + (a2 + a3)) * 0.17677669529663687f;
  }
  float m = fmaxf(fmaxf(sc[0], sc[1]), fmaxf(sc[2], sc[3]));
  float sum = 0.f;
  #pragma unroll
  for (int s = 0; s < 4; ++s){ sc[s] = __expf(sc[s] - m); sum += sc[s]; }
  float inv = 1.f / sum;

  float o[32];
  #pragma unroll
  for (int d = 0; d < 32; ++d) o[d] = 0.f;
  #pragma unroll
  for (int s = 0; s < 4; ++s){
    float p = sc[s] * inv;
    const ushort8* vp = (const ushort8*)(tb + (size_t)s * 768 + 512 + h * 32);
    #pragma unroll
    for (int g = 0; g < 4; ++g){
      ushort8 v = vp[g];
      #pragma unroll
      for (int e = 0; e < 8; ++e) o[g * 8 + e] += p * bf2f(v[e]);
    }
  }
  unsigned short* cp = ctx + (b * 4 + q) * 256 + h * 32;
  #pragma unroll
  for (int g = 0; g < 4; ++g){
    ushort8 w;
    #pragma unroll
    for (int e = 0; e < 8; ++e) w[e] = f2bf(o[g * 8 + e]);
    ((ushort8*)cp)[g] = w;
  }
}

// ---------------------------------------------------------------------------
// scatter: x2[b,c,:] = x[b,c,:] + ref[b, rid[c], :]   (bf16 out)
// ---------------------------------------------------------------------------
__global__ __launch_bounds__(256) void scatter_kernel(
    const float* __restrict__ x, const unsigned short* __restrict__ ref,
    unsigned short* __restrict__ x2)
{
  const int b = blockIdx.x, d = threadIdx.x;
  float rv[4];
  #pragma unroll
  for (int r = 0; r < 4; ++r) rv[r] = bf2f(ref[(size_t)b * 1024 + r * 256 + d]);
  const float* xb = x + (size_t)b * 4864 + d;
  unsigned short* xo = x2 + (size_t)b * 4864 + d;
  const int rid[19] = {0,0,1,2,3,0,3,3,0,0,0,1,2,3,0,3,3,1,2};
  #pragma unroll
  for (int c = 0; c < 19; ++c) xo[c * 256] = f2bf(xb[c * 256] + rv[rid[c]]);
}

// ---------------------------------------------------------------------------
// lsa attention v5: 19 tokens, 8 heads, 1 batch per 608-thread block
// (9.5 waves). Thread u: q = u>>5, h = (u>>2)&7, qt = u&3 -> owns 8 dims
// (d0 = h*32 + qt*8). K,V bf16 in LDS, injective spread off = slot*20 ushorts
// (slot = h*2 + (qt>>1)); score combine via shfl_xor 1,2 within the 4-lane
// qt-group. LDS 24,320B; qf[8]+p[19]+o[8] ~40 live floats.
// ---------------------------------------------------------------------------
__global__ __launch_bounds__(608) void attn19_kernel(
    const unsigned short* __restrict__ QKV, unsigned short* __restrict__ ctx)
{
  __shared__ unsigned short KV[38][320];      // rows 0..18 = K, 19..37 = V
  const int tid = threadIdx.x;
  const size_t b = blockIdx.x;
  const unsigned short* base = QKV + b * 19 * 768;

  // stage: 1216 chunks of 8 bf16 (2 per thread)
  #pragma unroll
  for (int it = 0; it < 2; ++it){
    int c = tid + it * 608;
    int m = (c >= 608);
    int i = c - m * 608;
    int s = i >> 5, j = i & 31;               // j: 8-elem chunk within 256
    ushort8 w = *(const ushort8*)(base + (size_t)s * 768 + 256 + (m << 8) + j * 8);
    int slot = j >> 1;                        // 0..15
    unsigned short* dst = &KV[m * 19 + s][slot * 20 + (j & 1) * 8];
    ushort4v lo = {w[0], w[1], w[2], w[3]};
    ushort4v hi = {w[4], w[5], w[6], w[7]};
    *(ushort4v*)dst = lo;
    *(ushort4v*)(dst + 4) = hi;
  }
  __syncthreads();

  const int q  = tid >> 5;
  const int h  = (tid >> 2) & 7;
  const int qt = tid & 3;
  const int roff = (h * 2 + (qt >> 1)) * 20 + (qt & 1) * 8;

  float qf[8];
  {
    ushort8 v = *(const ushort8*)(base + (size_t)q * 768 + h * 32 + qt * 8);
    #pragma unroll
    for (int e = 0; e < 8; ++e) qf[e] = bf2f(v[e]);
  }

  float p[19];
  float m = -1e30f;
  #pragma unroll
  for (int s = 0; s < 19; ++s){
    const unsigned short* kr = &KV[s][roff];
    ushort4v k0 = *(const ushort4v*)(kr);
    ushort4v k1 = *(const ushort4v*)(kr + 4);
    float a0 = qf[0]*bf2f(k0[0]) + qf[4]*bf2f(k1[0]);
    float a1 = qf[1]*bf2f(k0[1]) + qf[5]*bf2f(k1[1]);
    float a2 = qf[2]*bf2f(k0[2]) + qf[6]*bf2f(k1[2]);
    float a3 = qf[3]*bf2f(k0[3]) + qf[7]*bf2f(k1[3]);
    float part = (a0 + a1) + (a2 + a3);
    part += __shfl_xor(part, 1);
    part += __shfl_xor(part, 2);              // full 32-dim head dot
    p[s] = part * 0.17677669529663687f;
    m = fmaxf(m, p[s]);
  }
  float sum = 0.f;
  #pragma unroll
  for (int s = 0; s < 19; ++s){ p[s] = __expf(p[s] - m); sum += p[s]; }
  float inv = 1.f / sum;

  float o[8];
  #pragma unroll
  for (int d = 0; d < 8; ++d) o[d] = 0.f;
  #pragma unroll
  for (int s = 0; s < 19; ++s){
    float ps = p[s] * inv;
    const unsigned short* vr = &KV[19 + s][roff];
    ushort4v v0 = *(const ushort4v*)(vr);
    ushort4v v1 = *(const ushort4v*)(vr + 4);
    o[0] += ps * bf2f(v0[0]); o[1] += ps * bf2f(v0[1]);
    o[2] += ps * bf2f(v0[2]); o[3] += ps * bf2f(v0[3]);
    o[4] += ps * bf2f(v1[0]); o[5] += ps * bf2f(v1[1]);
    o[6] += ps * bf2f(v1[2]); o[7] += ps * bf2f(v1[3]);
  }
  ushort8 w;
  #pragma unroll
  for (int e = 0; e < 8; ++e) w[e] = f2bf(o[e]);
  *(ushort8*)(ctx + (b * 19 + q) * 256 + h * 32 + qt * 8) = w;
}

// ============================================================================
extern "C" void kernel_launch(void* const* d_in, const int* in_sizes, int n_in,
                              void* d_out, int out_size, void* d_ws, size_t ws_size,
                              hipStream_t stream)
{
  (void)n_in; (void)out_size;
  const float* x  = (const float*)d_in[0];
  const float* rq = (const float*)d_in[1];
  const float* rk = (const float*)d_in[2];
  const float* rv = (const float*)d_in[3];
  const float* ro = (const float*)d_in[4];
  const float* lq = (const float*)d_in[5];
  const float* lk = (const float*)d_in[6];
  const float* lv = (const float*)d_in[7];
  const float* lo = (const float*)d_in[8];
  const float* w1 = (const float*)d_in[9];
  const float* w2 = (const float*)d_in[10];

  const int B = in_sizes[0] / 4864;          // 4096
  const int M4  = B * 4;                     // 16384
  const int M19 = B * 19;                    // 77824
  const int MH  = M19 / 2;                   // 38912
  const size_t MB = 1ull << 20;
  if (ws_size < 240 * MB) return;

  char* ws = (char*)d_ws;
  unsigned short* WT    = (unsigned short*)(ws);
  unsigned short* FE    = (unsigned short*)(ws + 2   * MB);
  unsigned short* QKV4  = (unsigned short*)(ws + 10  * MB);
  unsigned short* CTX4  = (unsigned short*)(ws + 34  * MB);
  unsigned short* REF   = (unsigned short*)(ws + 42  * MB);
  unsigned short* X2    = (unsigned short*)(ws + 50  * MB);
  unsigned short* QKV19 = (unsigned short*)(ws + 88  * MB);
  unsigned short* CTX19 = (unsigned short*)(ws + 202 * MB);
  unsigned short* FUSED = (unsigned short*)(ws + 88  * MB);
  unsigned short* H     = (unsigned short*)(ws + 126 * MB);
  float* out = (float*)d_out;

  // grid helper for gemm_pw: ~512 blocks total, grid-stride over M
  auto pw_gx = [](int mtiles, int ny){ int g = 512 / ny; if (g > mtiles) g = mtiles; if (g < 1) g = 1; return g; };

  // 1. weights -> bf16 [n][k]
  wprep_all<<<4096, 256, 0, stream>>>(rq, rk, rv, ro, lq, lk, lv, lo, w1, w2, WT);
  // 2. region pool
  pool_kernel<<<B, 256, 0, stream>>>(x, FE);
  // 3. rsa QKV (concat, N=768, persistent-W)
  gemm_pw_kernel<0><<<dim3(pw_gx(M4/128, 6), 6), 256, 0, stream>>>(FE, WT, QKV4, 768, M4/128);
  // 4. rsa attention
  attn4_kernel<<<B/8, 256, 0, stream>>>(QKV4, CTX4);
  // 5. rsa out-proj + LN(.. + fe) -> REF
  gemm_ln_kernel<0><<<M4/64, 512, 0, stream>>>(CTX4, WT + 3*65536, FE, REF, M4, 256);
  // 6. x2 = x + ref[rid]
  scatter_kernel<<<B, 256, 0, stream>>>(x, REF, X2);
  // 7. lsa QKV (concat, N=768, persistent-W)
  gemm_pw_kernel<0><<<dim3(pw_gx(M19/128, 6), 6), 256, 0, stream>>>(X2, WT + 4*65536, QKV19, 768, M19/128);
  // 8. lsa attention
  attn19_kernel<<<B, 608, 0, stream>>>(QKV19, CTX19);
  // 9. lsa out-proj + LN(.. + x2) -> FUSED   (QKV19 dead)
  gemm_ln_kernel<0><<<M19/64, 512, 0, stream>>>(CTX19, WT + 7*65536, X2, FUSED, M19, 256);
  // 10. FFN halves: H = relu(FUSED @ w1) [persistent-W]; out = LN(H @ w2 + FUSED)
  for (int hf = 0; hf < 2; ++hf){
    const unsigned short* Fh = FUSED + (size_t)hf * MH * 256;
    gemm_pw_kernel<1><<<dim3(pw_gx(MH/128, 8), 8), 256, 0, stream>>>(Fh, WT + 524288, H, 1024, MH/128);
    gemm_ln_kernel<1><<<MH/64, 512, 0, stream>>>(H, WT + 786432, Fh,
                                                 out + (size_t)hf * MH * 256, MH, 1024);
  }
}

// Round 9
// 387.324 us; speedup vs baseline: 1.2274x; 1.2274x over previous
//
#include <hip/hip_runtime.h>
#include <stdint.h>
#include <stddef.h>

// ============================================================================
// RegionAttn fused pipeline v9 — consolidation of best-measured variants.
//  - gemm: round-7 single-buffer core + SPLIT epilogue (writes Q|K|V separate
//    buffers from one N=768 pass; segment is block-uniform since 128-col
//    panels are 256-aligned).
//  - attn4/attn19: round-2 versions verbatim (separate Q/K/V; attn19 = 60us).
//  - gemm_ln v2 (verified) for out-projs + FFN w2.
//
// Workspace map (MB offsets, sizes exact):
//   WT  @0(2)  FE @2(8)  Q4 @10(8)  K4 @18(8)  V4 @26(8)  CTX4 @34(8)
//   REF @42(8) X2 @50(38) Q19 @88(38) K19 @126(38) V19 @164(38) CTX19 @202(38)
//   FUSED @88 (alias Q19, dead)   H @126 (76MB, alias K19+V19, dead)
// Peak 240 MB.
// ============================================================================

#define DEVINL __device__ __forceinline__

typedef __attribute__((ext_vector_type(8))) short short8;
typedef __attribute__((ext_vector_type(4))) float floatx4;
typedef __attribute__((ext_vector_type(8))) unsigned short ushort8;
typedef __attribute__((ext_vector_type(4))) unsigned short ushort4v;

DEVINL float bf2f(unsigned short u){
  union { unsigned int i; float f; } x; x.i = ((unsigned int)u) << 16; return x.f;
}
DEVINL unsigned short f2bf(float f){
  union { float f; unsigned int i; } x; x.f = f;
  unsigned int r = x.i + 0x7fffu + ((x.i >> 16) & 1u);   // RNE
  return (unsigned short)(r >> 16);
}

typedef __attribute__((address_space(1))) void gvoid_t;
typedef __attribute__((address_space(3))) void lvoid_t;
DEVINL void gload_lds16(const void* g, void* l){
  __builtin_amdgcn_global_load_lds((gvoid_t*)g, (lvoid_t*)l, 16, 0, 0);
}

// ---------------------------------------------------------------------------
// Weight prep: fp32 [K][N] -> bf16 transposed [N][K].
// ---------------------------------------------------------------------------
__global__ __launch_bounds__(256) void wprep_all(
    const float* __restrict__ rq, const float* __restrict__ rk,
    const float* __restrict__ rv, const float* __restrict__ ro,
    const float* __restrict__ lq, const float* __restrict__ lk,
    const float* __restrict__ lv, const float* __restrict__ lo,
    const float* __restrict__ w1, const float* __restrict__ w2,
    unsigned short* __restrict__ wt)
{
  int idx = blockIdx.x * 256 + threadIdx.x;      // 0 .. 1048575
  const float* W; unsigned short* D; int N, r;
  const int K = (idx < 786432) ? 256 : 1024;
  if (idx < 524288){
    int wsel = idx >> 16; r = idx & 65535; N = 256; D = wt + wsel * 65536;
    switch (wsel){
      case 0: W = rq; break; case 1: W = rk; break; case 2: W = rv; break; case 3: W = ro; break;
      case 4: W = lq; break; case 5: W = lk; break; case 6: W = lv; break; default: W = lo; break;
    }
  } else if (idx < 786432){
    r = idx - 524288; N = 1024; D = wt + 524288; W = w1;
  } else {
    r = idx - 786432; N = 256; D = wt + 786432; W = w2;
  }
  int k = r / N, n = r - k * N;
  D[(size_t)n * K + k] = f2bf(W[r]);
}

// ---------------------------------------------------------------------------
// Region avg-pool: x fp32 [B,19,256] -> fe bf16 [B,4,256]
// ---------------------------------------------------------------------------
__global__ __launch_bounds__(256) void pool_kernel(const float* __restrict__ x,
                                                   unsigned short* __restrict__ fe)
{
  const int b = blockIdx.x, d = threadIdx.x;
  const float* xb = x + (size_t)b * 4864 + d;
  float s0 = xb[0*256]+xb[1*256]+xb[5*256]+xb[8*256]+xb[9*256]+xb[10*256]+xb[14*256];
  float s1 = xb[2*256]+xb[11*256]+xb[17*256];
  float s2 = xb[3*256]+xb[12*256]+xb[18*256];
  float s3 = xb[4*256]+xb[6*256]+xb[7*256]+xb[13*256]+xb[15*256]+xb[16*256];
  unsigned short* fb = fe + (size_t)b * 1024 + d;
  fb[0]   = f2bf(s0 * (1.f/7.f));
  fb[256] = f2bf(s1 * (1.f/3.f));
  fb[512] = f2bf(s2 * (1.f/3.f));
  fb[768] = f2bf(s3 * (1.f/6.f));
}

// ---------------------------------------------------------------------------
// GEMM (round-7 single-buffer core): C = act(A[M,K] @ Bt[N,K]^T).
// BM=BN=128, BK=64, 4 waves, 32KB LDS, 2 barriers/K-step, 3 blocks/CU.
// SPLIT=1: N must be 768 and output goes to C0|C1|C2 ([M,256] each) chosen by
// the (block-uniform) 256-segment of the column panel. SPLIT=0: C0 with ldc=N.
// ---------------------------------------------------------------------------
template<int RELU, int SPLIT>
__global__ __launch_bounds__(256, 3)
void gemm_kernel(const unsigned short* __restrict__ A,
                 const unsigned short* __restrict__ Bt,
                 unsigned short* __restrict__ C0,
                 unsigned short* __restrict__ C1,
                 unsigned short* __restrict__ C2,
                 int M, int N, int K)
{
  __shared__ __align__(1024) unsigned short lds[2][8192];  // A 16KB, B 16KB
  const int tid  = threadIdx.x;
  const int wave = tid >> 6, lane = tid & 63;
  const int wm = wave >> 1, wn = wave & 1;
  const int rowA0 = blockIdx.x * 128;
  const int rowB0 = blockIdx.y * 128;
  const int stg_row = lane >> 3;
  const int stg_kb  = (((lane & 7) ^ (lane >> 3)) << 4);

  floatx4 acc[4][4];
  #pragma unroll
  for (int i = 0; i < 4; ++i)
    #pragma unroll
    for (int j = 0; j < 4; ++j) acc[i][j] = (floatx4){0.f, 0.f, 0.f, 0.f};

  const int nk = K >> 6;
  for (int kt = 0; kt < nk; ++kt){
    if (kt) __syncthreads();
    const int kbase = kt << 7;
    #pragma unroll
    for (int s = 0; s < 4; ++s){
      int chunk = wave * 4 + s;
      int r = chunk * 8 + stg_row;
      gload_lds16((const char*)(A  + (size_t)(rowA0 + r) * K) + kbase + stg_kb,
                  (char*)(&lds[0][0]) + chunk * 1024);
      gload_lds16((const char*)(Bt + (size_t)(rowB0 + r) * K) + kbase + stg_kb,
                  (char*)(&lds[1][0]) + chunk * 1024);
    }
    __syncthreads();
    const char* As = (const char*)(&lds[0][0]);
    const char* Bs = (const char*)(&lds[1][0]);
    #pragma unroll
    for (int kk = 0; kk < 2; ++kk){
      short8 a[4], b[4];
      #pragma unroll
      for (int i = 0; i < 4; ++i){
        int row = wm * 64 + i * 16 + (lane & 15);
        int kb  = (kk * 64 + ((lane >> 4) << 4)) ^ ((row & 7) << 4);
        a[i] = *(const short8*)(As + row * 128 + kb);
      }
      #pragma unroll
      for (int j = 0; j < 4; ++j){
        int row = wn * 64 + j * 16 + (lane & 15);
        int kb  = (kk * 64 + ((lane >> 4) << 4)) ^ ((row & 7) << 4);
        b[j] = *(const short8*)(Bs + row * 128 + kb);
      }
      #pragma unroll
      for (int i = 0; i < 4; ++i)
        #pragma unroll
        for (int j = 0; j < 4; ++j)
          acc[i][j] = __builtin_amdgcn_mfma_f32_16x16x32_bf16(a[i], b[j], acc[i][j], 0, 0, 0);
    }
  }

  // epilogue: block-uniform destination segment when SPLIT
  unsigned short* dst;
  int colb, ldc;
  if (SPLIT){
    const int seg = rowB0 >> 8;
    dst = (seg == 0) ? C0 : (seg == 1) ? C1 : C2;
    colb = rowB0 & 255;
    ldc = 256;
  } else {
    dst = C0; colb = rowB0; ldc = N;
  }
  const int cr = (lane >> 4) << 2;
  const int cc = lane & 15;
  #pragma unroll
  for (int i = 0; i < 4; ++i){
    #pragma unroll
    for (int j = 0; j < 4; ++j){
      int r0 = rowA0 + wm * 64 + i * 16 + cr;
      int c0 = colb + wn * 64 + j * 16 + cc;
      #pragma unroll
      for (int r = 0; r < 4; ++r){
        float v = acc[i][j][r];
        if (RELU) v = fmaxf(v, 0.f);
        dst[(size_t)(r0 + r) * ldc + c0] = f2bf(v);
      }
    }
  }
}

// ---------------------------------------------------------------------------
// gemm_ln v2: Out[M,256] = LN(A[M,K] @ Bt[256,K]^T + Res[M,256]).
// BM=64, BN=256, BK=64, 512 thr (8 waves 2x4). (verified; unchanged)
// ---------------------------------------------------------------------------
template<int OUTF32>
__global__ __launch_bounds__(512, 4)
void gemm_ln_kernel(const unsigned short* __restrict__ A,
                    const unsigned short* __restrict__ Bt,
                    const unsigned short* __restrict__ Res,
                    void* __restrict__ Out, int M, int K)
{
  __shared__ __align__(1024) char lds[2][40960];   // A@0 (8KB), B@8192 (32KB)
  const int tid  = threadIdx.x;
  const int wave = tid >> 6, lane = tid & 63;
  const int wm = wave >> 2, wn = wave & 3;
  const int rowA0 = blockIdx.x * 64;
  const int stg_row = lane >> 3;
  const int stg_kb  = (((lane & 7) ^ (lane >> 3)) << 4);

  floatx4 acc[2][4];
  #pragma unroll
  for (int i = 0; i < 2; ++i)
    #pragma unroll
    for (int j = 0; j < 4; ++j) acc[i][j] = (floatx4){0.f, 0.f, 0.f, 0.f};

  const int nk = K >> 6;
  int cur = 0;
  #pragma unroll
  for (int s = 0; s < 5; ++s){
    int chunk = wave * 5 + s;
    const unsigned short* src = (chunk < 8)
      ? A  + (size_t)(rowA0 + chunk * 8 + stg_row) * K
      : Bt + (size_t)((chunk - 8) * 8 + stg_row) * K;
    gload_lds16((const char*)src + stg_kb, &lds[0][0] + chunk * 1024);
  }
  __syncthreads();

  for (int kt = 0; kt < nk; ++kt){
    if (kt + 1 < nk){
      const int kbase = (kt + 1) << 7;
      #pragma unroll
      for (int s = 0; s < 5; ++s){
        int chunk = wave * 5 + s;
        const unsigned short* src = (chunk < 8)
          ? A  + (size_t)(rowA0 + chunk * 8 + stg_row) * K
          : Bt + (size_t)((chunk - 8) * 8 + stg_row) * K;
        gload_lds16((const char*)src + kbase + stg_kb, &lds[cur ^ 1][0] + chunk * 1024);
      }
    }
    const char* As = &lds[cur][0];
    const char* Bs = &lds[cur][0] + 8192;
    #pragma unroll
    for (int kk = 0; kk < 2; ++kk){
      short8 a[2], b[4];
      #pragma unroll
      for (int i = 0; i < 2; ++i){
        int row = wm * 32 + i * 16 + (lane & 15);
        int kb  = (kk * 64 + ((lane >> 4) << 4)) ^ ((row & 7) << 4);
        a[i] = *(const short8*)(As + row * 128 + kb);
      }
      #pragma unroll
      for (int j = 0; j < 4; ++j){
        int row = wn * 64 + j * 16 + (lane & 15);
        int kb  = (kk * 64 + ((lane >> 4) << 4)) ^ ((row & 7) << 4);
        b[j] = *(const short8*)(Bs + row * 128 + kb);
      }
      #pragma unroll
      for (int i = 0; i < 2; ++i)
        #pragma unroll
        for (int j = 0; j < 4; ++j)
          acc[i][j] = __builtin_amdgcn_mfma_f32_16x16x32_bf16(a[i], b[j], acc[i][j], 0, 0, 0);
    }
    __syncthreads();
    cur ^= 1;
  }

  float* red_s = (float*)&lds[0][0];     // [4][64]
  float* red_q = red_s + 256;            // [4][64]
  float* mu_a  = red_s + 512;            // [64]
  float* rs_a  = red_s + 576;            // [64]
  const int g  = lane >> 4;
  const int cl = lane & 15;
  #pragma unroll
  for (int i = 0; i < 2; ++i){
    #pragma unroll
    for (int r = 0; r < 4; ++r){
      const int rowl = wm * 32 + i * 16 + g * 4 + r;
      float s = 0.f, q = 0.f;
      #pragma unroll
      for (int j = 0; j < 4; ++j){
        float v = acc[i][j][r] +
                  bf2f(Res[(size_t)(rowA0 + rowl) * 256 + wn * 64 + j * 16 + cl]);
        acc[i][j][r] = v;
        s += v; q += v * v;
      }
      #pragma unroll
      for (int off = 1; off < 16; off <<= 1){
        s += __shfl_xor(s, off); q += __shfl_xor(q, off);
      }
      if (cl == 0){ red_s[wn * 64 + rowl] = s; red_q[wn * 64 + rowl] = q; }
    }
  }
  __syncthreads();
  if (tid < 64){
    float S = red_s[tid] + red_s[64 + tid] + red_s[128 + tid] + red_s[192 + tid];
    float Q = red_q[tid] + red_q[64 + tid] + red_q[128 + tid] + red_q[192 + tid];
    float mu = S * (1.f / 256.f);
    float var = Q * (1.f / 256.f) - mu * mu;
    mu_a[tid] = mu;
    rs_a[tid] = rsqrtf(var + 1e-5f);
  }
  __syncthreads();
  #pragma unroll
  for (int i = 0; i < 2; ++i){
    #pragma unroll
    for (int r = 0; r < 4; ++r){
      const int rowl = wm * 32 + i * 16 + g * 4 + r;
      const float mu = mu_a[rowl], rs = rs_a[rowl];
      #pragma unroll
      for (int j = 0; j < 4; ++j){
        float w = (acc[i][j][r] - mu) * rs;
        size_t idx = (size_t)(rowA0 + rowl) * 256 + wn * 64 + j * 16 + cl;
        if (OUTF32) ((float*)Out)[idx] = w;
        else        ((unsigned short*)Out)[idx] = f2bf(w);
      }
    }
  }
}

// ---------------------------------------------------------------------------
// rsa attention (round-2 verbatim): 4 tokens, 8 heads; separate Q/K/V.
// ---------------------------------------------------------------------------
__global__ __launch_bounds__(256) void attn4_kernel(
    const unsigned short* __restrict__ Q, const unsigned short* __restrict__ K,
    const unsigned short* __restrict__ V, unsigned short* __restrict__ ctx)
{
  const int t = threadIdx.x;
  const int lb = t >> 5, u = t & 31, h = u >> 2, q = u & 3;
  const size_t b = (size_t)blockIdx.x * 8 + lb;
  const size_t base = b * 1024 + h * 32;

  float qf[32];
  {
    const ushort8* qp = (const ushort8*)(Q + base + q * 256);
    #pragma unroll
    for (int g = 0; g < 4; ++g){
      ushort8 v = qp[g];
      #pragma unroll
      for (int e = 0; e < 8; ++e) qf[g * 8 + e] = bf2f(v[e]);
    }
  }
  float sc[4];
  #pragma unroll
  for (int s = 0; s < 4; ++s){
    const ushort8* kp = (const ushort8*)(K + base + s * 256);
    float a0 = 0, a1 = 0, a2 = 0, a3 = 0;
    #pragma unroll
    for (int g = 0; g < 4; ++g){
      ushort8 v = kp[g];
      a0 += qf[g*8+0]*bf2f(v[0]); a1 += qf[g*8+1]*bf2f(v[1]);
      a2 += qf[g*8+2]*bf2f(v[2]); a3 += qf[g*8+3]*bf2f(v[3]);
      a0 += qf[g*8+4]*bf2f(v[4]); a1 += qf[g*8+5]*bf2f(v[5]);
      a2 += qf[g*8+6]*bf2f(v[6]); a3 += qf[g*8+7]*bf2f(v[7]);
    }
    sc[s] = ((a0 + a1) + (a2 + a3)) * 0.17677669529663687f;
  }
  float m = fmaxf(fmaxf(sc[0], sc[1]), fmaxf(sc[2], sc[3]));
  float sum = 0.f;
  #pragma unroll
  for (int s = 0; s < 4; ++s){ sc[s] = __expf(sc[s] - m); sum += sc[s]; }
  float inv = 1.f / sum;

  float o[32];
  #pragma unroll
  for (int d = 0; d < 32; ++d) o[d] = 0.f;
  #pragma unroll
  for (int s = 0; s < 4; ++s){
    float p = sc[s] * inv;
    const ushort8* vp = (const ushort8*)(V + base + s * 256);
    #pragma unroll
    for (int g = 0; g < 4; ++g){
      ushort8 v = vp[g];
      #pragma unroll
      for (int e = 0; e < 8; ++e) o[g * 8 + e] += p * bf2f(v[e]);
    }
  }
  unsigned short* cp = ctx + base + q * 256;
  #pragma unroll
  for (int g = 0; g < 4; ++g){
    ushort8 w;
    #pragma unroll
    for (int e = 0; e < 8; ++e) w[e] = f2bf(o[g * 8 + e]);
    ((ushort8*)cp)[g] = w;
  }
}

// ---------------------------------------------------------------------------
// scatter: x2[b,c,:] = x[b,c,:] + ref[b, rid[c], :]   (bf16 out)
// ---------------------------------------------------------------------------
__global__ __launch_bounds__(256) void scatter_kernel(
    const float* __restrict__ x, const unsigned short* __restrict__ ref,
    unsigned short* __restrict__ x2)
{
  const int b = blockIdx.x, d = threadIdx.x;
  float rv[4];
  #pragma unroll
  for (int r = 0; r < 4; ++r) rv[r] = bf2f(ref[(size_t)b * 1024 + r * 256 + d]);
  const float* xb = x + (size_t)b * 4864 + d;
  unsigned short* xo = x2 + (size_t)b * 4864 + d;
  const int rid[19] = {0,0,1,2,3,0,3,3,0,0,0,1,2,3,0,3,3,1,2};
  #pragma unroll
  for (int c = 0; c < 19; ++c) xo[c * 256] = f2bf(xb[c * 256] + rv[rid[c]]);
}

// ---------------------------------------------------------------------------
// lsa attention (round-2 verbatim, best measured 60us): 19 tokens, 8 heads.
// One block/batch; K,V fp32 in LDS; threads 0..151 = (h,q).
// ---------------------------------------------------------------------------
__global__ __launch_bounds__(256) void attn19_kernel(
    const unsigned short* __restrict__ Q, const unsigned short* __restrict__ K,
    const unsigned short* __restrict__ V, unsigned short* __restrict__ ctx)
{
  __shared__ float Kl[4864];
  __shared__ float Vl[4864];
  const size_t b = blockIdx.x;
  const unsigned short* Kb = K + b * 4864;
  const unsigned short* Vb = V + b * 4864;
  for (int i = threadIdx.x; i < 4864; i += 256){ Kl[i] = bf2f(Kb[i]); Vl[i] = bf2f(Vb[i]); }
  __syncthreads();
  const int t = threadIdx.x;
  if (t >= 152) return;
  const int h = t / 19, qq = t - h * 19;

  float qf[32];
  {
    const ushort8* qp = (const ushort8*)(Q + b * 4864 + qq * 256 + h * 32);
    #pragma unroll
    for (int g = 0; g < 4; ++g){
      ushort8 v = qp[g];
      #pragma unroll
      for (int e = 0; e < 8; ++e) qf[g * 8 + e] = bf2f(v[e]);
    }
  }
  float p[19];
  float m = -1e30f;
  #pragma unroll
  for (int s = 0; s < 19; ++s){
    const float* kr = &Kl[s * 256 + h * 32];
    float a0 = 0, a1 = 0, a2 = 0, a3 = 0;
    #pragma unroll
    for (int d = 0; d < 32; d += 4){
      a0 += qf[d+0] * kr[d+0]; a1 += qf[d+1] * kr[d+1];
      a2 += qf[d+2] * kr[d+2]; a3 += qf[d+3] * kr[d+3];
    }
    p[s] = ((a0 + a1) + (a2 + a3)) * 0.17677669529663687f;
    m = fmaxf(m, p[s]);
  }
  float sum = 0.f;
  #pragma unroll
  for (int s = 0; s < 19; ++s){ p[s] = __expf(p[s] - m); sum += p[s]; }
  float inv = 1.f / sum;

  float o[32];
  #pragma unroll
  for (int d = 0; d < 32; ++d) o[d] = 0.f;
  #pragma unroll
  for (int s = 0; s < 19; ++s){
    float ps = p[s] * inv;
    const float* vr = &Vl[s * 256 + h * 32];
    #pragma unroll
    for (int d = 0; d < 32; ++d) o[d] += ps * vr[d];
  }
  unsigned short* cp = ctx + b * 4864 + qq * 256 + h * 32;
  #pragma unroll
  for (int g = 0; g < 4; ++g){
    ushort8 w;
    #pragma unroll
    for (int e = 0; e < 8; ++e) w[e] = f2bf(o[g * 8 + e]);
    ((ushort8*)cp)[g] = w;
  }
}

// ============================================================================
extern "C" void kernel_launch(void* const* d_in, const int* in_sizes, int n_in,
                              void* d_out, int out_size, void* d_ws, size_t ws_size,
                              hipStream_t stream)
{
  (void)n_in; (void)out_size;
  const float* x  = (const float*)d_in[0];
  const float* rq = (const float*)d_in[1];
  const float* rk = (const float*)d_in[2];
  const float* rv = (const float*)d_in[3];
  const float* ro = (const float*)d_in[4];
  const float* lq = (const float*)d_in[5];
  const float* lk = (const float*)d_in[6];
  const float* lv = (const float*)d_in[7];
  const float* lo = (const float*)d_in[8];
  const float* w1 = (const float*)d_in[9];
  const float* w2 = (const float*)d_in[10];

  const int B = in_sizes[0] / 4864;          // 4096
  const int M4  = B * 4;                     // 16384
  const int M19 = B * 19;                    // 77824
  const int MH  = M19 / 2;                   // 38912
  const size_t MB = 1ull << 20;
  if (ws_size < 240 * MB) return;

  char* ws = (char*)d_ws;
  unsigned short* WT    = (unsigned short*)(ws);
  unsigned short* FE    = (unsigned short*)(ws + 2   * MB);
  unsigned short* Q4    = (unsigned short*)(ws + 10  * MB);
  unsigned short* K4    = (unsigned short*)(ws + 18  * MB);
  unsigned short* V4    = (unsigned short*)(ws + 26  * MB);
  unsigned short* CTX4  = (unsigned short*)(ws + 34  * MB);
  unsigned short* REF   = (unsigned short*)(ws + 42  * MB);
  unsigned short* X2    = (unsigned short*)(ws + 50  * MB);
  unsigned short* Q19   = (unsigned short*)(ws + 88  * MB);
  unsigned short* K19   = (unsigned short*)(ws + 126 * MB);
  unsigned short* V19   = (unsigned short*)(ws + 164 * MB);
  unsigned short* CTX19 = (unsigned short*)(ws + 202 * MB);
  unsigned short* FUSED = (unsigned short*)(ws + 88  * MB);  // alias Q19 (dead)
  unsigned short* H     = (unsigned short*)(ws + 126 * MB);  // alias K19+V19 (dead)
  float* out = (float*)d_out;

  // 1. weights -> bf16 [n][k]
  wprep_all<<<4096, 256, 0, stream>>>(rq, rk, rv, ro, lq, lk, lv, lo, w1, w2, WT);
  // 2. region pool
  pool_kernel<<<B, 256, 0, stream>>>(x, FE);
  // 3. rsa QKV (one pass, split epilogue -> Q4,K4,V4)
  gemm_kernel<0,1><<<dim3(M4/128, 6), 256, 0, stream>>>(FE, WT, Q4, K4, V4, M4, 768, 256);
  // 4. rsa attention
  attn4_kernel<<<B/8, 256, 0, stream>>>(Q4, K4, V4, CTX4);
  // 5. rsa out-proj + LN(.. + fe) -> REF
  gemm_ln_kernel<0><<<M4/64, 512, 0, stream>>>(CTX4, WT + 3*65536, FE, REF, M4, 256);
  // 6. x2 = x + ref[rid]
  scatter_kernel<<<B, 256, 0, stream>>>(x, REF, X2);
  // 7. lsa QKV (one pass, split epilogue -> Q19,K19,V19)
  gemm_kernel<0,1><<<dim3(M19/128, 6), 256, 0, stream>>>(X2, WT + 4*65536, Q19, K19, V19, M19, 768, 256);
  // 8. lsa attention
  attn19_kernel<<<B, 256, 0, stream>>>(Q19, K19, V19, CTX19);
  // 9. lsa out-proj + LN(.. + x2) -> FUSED   (Q19 dead)
  gemm_ln_kernel<0><<<M19/64, 512, 0, stream>>>(CTX19, WT + 7*65536, X2, FUSED, M19, 256);
  // 10. FFN halves: H = relu(FUSED @ w1); out = LN(H @ w2 + FUSED)
  for (int hf = 0; hf < 2; ++hf){
    const unsigned short* Fh = FUSED + (size_t)hf * MH * 256;
    gemm_kernel<1,0><<<dim3(MH/128, 8), 256, 0, stream>>>(Fh, WT + 524288, H, nullptr, nullptr, MH, 1024, 256);
    gemm_ln_kernel<1><<<MH/64, 512, 0, stream>>>(H, WT + 786432, Fh,
                                                 out + (size_t)hf * MH * 256, MH, 1024);
  }
}

// Round 10
// 367.597 us; speedup vs baseline: 1.2933x; 1.0537x over previous
//
#include <hip/hip_runtime.h>
#include <stdint.h>
#include <stddef.h>

// ============================================================================
// RegionAttn fused pipeline v10.
//  - gemm: round-7 single-buffer core + 1-D XCD-chunked swizzled grid
//    (panel-fastest) so same-A-tile blocks run on the SAME XCD -> A read from
//    HBM once, panel re-reads are L2 hits.  SPLIT epilogue as v9.
//  - attn19: round-2 structure + VECTORIZED staging (ushort8, 16B/lane).
//  - attn4 / gemm_ln / rest: v9 verbatim (verified).
//
// Workspace map (MB offsets, sizes exact):
//   WT  @0(2)  FE @2(8)  Q4 @10(8)  K4 @18(8)  V4 @26(8)  CTX4 @34(8)
//   REF @42(8) X2 @50(38) Q19 @88(38) K19 @126(38) V19 @164(38) CTX19 @202(38)
//   FUSED @88 (alias Q19, dead)   H @126 (76MB, alias K19+V19, dead)
// Peak 240 MB.
// ============================================================================

#define DEVINL __device__ __forceinline__

typedef __attribute__((ext_vector_type(8))) short short8;
typedef __attribute__((ext_vector_type(4))) float floatx4;
typedef __attribute__((ext_vector_type(8))) unsigned short ushort8;
typedef __attribute__((ext_vector_type(4))) unsigned short ushort4v;

DEVINL float bf2f(unsigned short u){
  union { unsigned int i; float f; } x; x.i = ((unsigned int)u) << 16; return x.f;
}
DEVINL unsigned short f2bf(float f){
  union { float f; unsigned int i; } x; x.f = f;
  unsigned int r = x.i + 0x7fffu + ((x.i >> 16) & 1u);   // RNE
  return (unsigned short)(r >> 16);
}

typedef __attribute__((address_space(1))) void gvoid_t;
typedef __attribute__((address_space(3))) void lvoid_t;
DEVINL void gload_lds16(const void* g, void* l){
  __builtin_amdgcn_global_load_lds((gvoid_t*)g, (lvoid_t*)l, 16, 0, 0);
}

// ---------------------------------------------------------------------------
// Weight prep: fp32 [K][N] -> bf16 transposed [N][K].
// ---------------------------------------------------------------------------
__global__ __launch_bounds__(256) void wprep_all(
    const float* __restrict__ rq, const float* __restrict__ rk,
    const float* __restrict__ rv, const float* __restrict__ ro,
    const float* __restrict__ lq, const float* __restrict__ lk,
    const float* __restrict__ lv, const float* __restrict__ lo,
    const float* __restrict__ w1, const float* __restrict__ w2,
    unsigned short* __restrict__ wt)
{
  int idx = blockIdx.x * 256 + threadIdx.x;      // 0 .. 1048575
  const float* W; unsigned short* D; int N, r;
  const int K = (idx < 786432) ? 256 : 1024;
  if (idx < 524288){
    int wsel = idx >> 16; r = idx & 65535; N = 256; D = wt + wsel * 65536;
    switch (wsel){
      case 0: W = rq; break; case 1: W = rk; break; case 2: W = rv; break; case 3: W = ro; break;
      case 4: W = lq; break; case 5: W = lk; break; case 6: W = lv; break; default: W = lo; break;
    }
  } else if (idx < 786432){
    r = idx - 524288; N = 1024; D = wt + 524288; W = w1;
  } else {
    r = idx - 786432; N = 256; D = wt + 786432; W = w2;
  }
  int k = r / N, n = r - k * N;
  D[(size_t)n * K + k] = f2bf(W[r]);
}

// ---------------------------------------------------------------------------
// Region avg-pool: x fp32 [B,19,256] -> fe bf16 [B,4,256]
// ---------------------------------------------------------------------------
__global__ __launch_bounds__(256) void pool_kernel(const float* __restrict__ x,
                                                   unsigned short* __restrict__ fe)
{
  const int b = blockIdx.x, d = threadIdx.x;
  const float* xb = x + (size_t)b * 4864 + d;
  float s0 = xb[0*256]+xb[1*256]+xb[5*256]+xb[8*256]+xb[9*256]+xb[10*256]+xb[14*256];
  float s1 = xb[2*256]+xb[11*256]+xb[17*256];
  float s2 = xb[3*256]+xb[12*256]+xb[18*256];
  float s3 = xb[4*256]+xb[6*256]+xb[7*256]+xb[13*256]+xb[15*256]+xb[16*256];
  unsigned short* fb = fe + (size_t)b * 1024 + d;
  fb[0]   = f2bf(s0 * (1.f/7.f));
  fb[256] = f2bf(s1 * (1.f/3.f));
  fb[512] = f2bf(s2 * (1.f/3.f));
  fb[768] = f2bf(s3 * (1.f/6.f));
}

// ---------------------------------------------------------------------------
// GEMM (single-buffer core, v9): C = act(A[M,K] @ Bt[N,K]^T).
// 1-D grid of NPAN*mtiles blocks (must be %8==0). XCD-chunk swizzle:
// g = (o&7)*(nwg/8) + (o>>3)  [bijective since nwg%8==0]; then
// panel = g % NPAN (fastest), mtile = g / NPAN -> the NPAN blocks sharing an
// A-tile run consecutively on ONE XCD => A-tile is an L2 hit after first use.
// SPLIT=1: N==768, output to C0|C1|C2 [M,256] by 256-segment (block-uniform).
// ---------------------------------------------------------------------------
template<int RELU, int SPLIT, int NPAN>
__global__ __launch_bounds__(256, 3)
void gemm_kernel(const unsigned short* __restrict__ A,
                 const unsigned short* __restrict__ Bt,
                 unsigned short* __restrict__ C0,
                 unsigned short* __restrict__ C1,
                 unsigned short* __restrict__ C2,
                 int M, int N, int K)
{
  __shared__ __align__(1024) unsigned short lds[2][8192];  // A 16KB, B 16KB
  const int tid  = threadIdx.x;
  const int wave = tid >> 6, lane = tid & 63;
  const int wm = wave >> 1, wn = wave & 1;

  const int nwg = gridDim.x;
  const int o = blockIdx.x;
  const int g = ((o & 7) * (nwg >> 3)) + (o >> 3);   // XCD-chunked id
  const int rowA0 = (g / NPAN) * 128;
  const int rowB0 = (g % NPAN) * 128;

  const int stg_row = lane >> 3;
  const int stg_kb  = (((lane & 7) ^ (lane >> 3)) << 4);

  floatx4 acc[4][4];
  #pragma unroll
  for (int i = 0; i < 4; ++i)
    #pragma unroll
    for (int j = 0; j < 4; ++j) acc[i][j] = (floatx4){0.f, 0.f, 0.f, 0.f};

  const int nk = K >> 6;
  for (int kt = 0; kt < nk; ++kt){
    if (kt) __syncthreads();
    const int kbase = kt << 7;
    #pragma unroll
    for (int s = 0; s < 4; ++s){
      int chunk = wave * 4 + s;
      int r = chunk * 8 + stg_row;
      gload_lds16((const char*)(A  + (size_t)(rowA0 + r) * K) + kbase + stg_kb,
                  (char*)(&lds[0][0]) + chunk * 1024);
      gload_lds16((const char*)(Bt + (size_t)(rowB0 + r) * K) + kbase + stg_kb,
                  (char*)(&lds[1][0]) + chunk * 1024);
    }
    __syncthreads();
    const char* As = (const char*)(&lds[0][0]);
    const char* Bs = (const char*)(&lds[1][0]);
    #pragma unroll
    for (int kk = 0; kk < 2; ++kk){
      short8 a[4], b[4];
      #pragma unroll
      for (int i = 0; i < 4; ++i){
        int row = wm * 64 + i * 16 + (lane & 15);
        int kb  = (kk * 64 + ((lane >> 4) << 4)) ^ ((row & 7) << 4);
        a[i] = *(const short8*)(As + row * 128 + kb);
      }
      #pragma unroll
      for (int j = 0; j < 4; ++j){
        int row = wn * 64 + j * 16 + (lane & 15);
        int kb  = (kk * 64 + ((lane >> 4) << 4)) ^ ((row & 7) << 4);
        b[j] = *(const short8*)(Bs + row * 128 + kb);
      }
      #pragma unroll
      for (int i = 0; i < 4; ++i)
        #pragma unroll
        for (int j = 0; j < 4; ++j)
          acc[i][j] = __builtin_amdgcn_mfma_f32_16x16x32_bf16(a[i], b[j], acc[i][j], 0, 0, 0);
    }
  }

  unsigned short* dst;
  int colb, ldc;
  if (SPLIT){
    const int seg = rowB0 >> 8;
    dst = (seg == 0) ? C0 : (seg == 1) ? C1 : C2;
    colb = rowB0 & 255;
    ldc = 256;
  } else {
    dst = C0; colb = rowB0; ldc = N;
  }
  const int cr = (lane >> 4) << 2;
  const int cc = lane & 15;
  #pragma unroll
  for (int i = 0; i < 4; ++i){
    #pragma unroll
    for (int j = 0; j < 4; ++j){
      int r0 = rowA0 + wm * 64 + i * 16 + cr;
      int c0 = colb + wn * 64 + j * 16 + cc;
      #pragma unroll
      for (int r = 0; r < 4; ++r){
        float v = acc[i][j][r];
        if (RELU) v = fmaxf(v, 0.f);
        dst[(size_t)(r0 + r) * ldc + c0] = f2bf(v);
      }
    }
  }
}

// ---------------------------------------------------------------------------
// gemm_ln v2: Out[M,256] = LN(A[M,K] @ Bt[256,K]^T + Res[M,256]).
// BM=64, BN=256, BK=64, 512 thr (8 waves 2x4). (verified; unchanged)
// ---------------------------------------------------------------------------
template<int OUTF32>
__global__ __launch_bounds__(512, 4)
void gemm_ln_kernel(const unsigned short* __restrict__ A,
                    const unsigned short* __restrict__ Bt,
                    const unsigned short* __restrict__ Res,
                    void* __restrict__ Out, int M, int K)
{
  __shared__ __align__(1024) char lds[2][40960];   // A@0 (8KB), B@8192 (32KB)
  const int tid  = threadIdx.x;
  const int wave = tid >> 6, lane = tid & 63;
  const int wm = wave >> 2, wn = wave & 3;
  const int rowA0 = blockIdx.x * 64;
  const int stg_row = lane >> 3;
  const int stg_kb  = (((lane & 7) ^ (lane >> 3)) << 4);

  floatx4 acc[2][4];
  #pragma unroll
  for (int i = 0; i < 2; ++i)
    #pragma unroll
    for (int j = 0; j < 4; ++j) acc[i][j] = (floatx4){0.f, 0.f, 0.f, 0.f};

  const int nk = K >> 6;
  int cur = 0;
  #pragma unroll
  for (int s = 0; s < 5; ++s){
    int chunk = wave * 5 + s;
    const unsigned short* src = (chunk < 8)
      ? A  + (size_t)(rowA0 + chunk * 8 + stg_row) * K
      : Bt + (size_t)((chunk - 8) * 8 + stg_row) * K;
    gload_lds16((const char*)src + stg_kb, &lds[0][0] + chunk * 1024);
  }
  __syncthreads();

  for (int kt = 0; kt < nk; ++kt){
    if (kt + 1 < nk){
      const int kbase = (kt + 1) << 7;
      #pragma unroll
      for (int s = 0; s < 5; ++s){
        int chunk = wave * 5 + s;
        const unsigned short* src = (chunk < 8)
          ? A  + (size_t)(rowA0 + chunk * 8 + stg_row) * K
          : Bt + (size_t)((chunk - 8) * 8 + stg_row) * K;
        gload_lds16((const char*)src + kbase + stg_kb, &lds[cur ^ 1][0] + chunk * 1024);
      }
    }
    const char* As = &lds[cur][0];
    const char* Bs = &lds[cur][0] + 8192;
    #pragma unroll
    for (int kk = 0; kk < 2; ++kk){
      short8 a[2], b[4];
      #pragma unroll
      for (int i = 0; i < 2; ++i){
        int row = wm * 32 + i * 16 + (lane & 15);
        int kb  = (kk * 64 + ((lane >> 4) << 4)) ^ ((row & 7) << 4);
        a[i] = *(const short8*)(As + row * 128 + kb);
      }
      #pragma unroll
      for (int j = 0; j < 4; ++j){
        int row = wn * 64 + j * 16 + (lane & 15);
        int kb  = (kk * 64 + ((lane >> 4) << 4)) ^ ((row & 7) << 4);
        b[j] = *(const short8*)(Bs + row * 128 + kb);
      }
      #pragma unroll
      for (int i = 0; i < 2; ++i)
        #pragma unroll
        for (int j = 0; j < 4; ++j)
          acc[i][j] = __builtin_amdgcn_mfma_f32_16x16x32_bf16(a[i], b[j], acc[i][j], 0, 0, 0);
    }
    __syncthreads();
    cur ^= 1;
  }

  float* red_s = (float*)&lds[0][0];     // [4][64]
  float* red_q = red_s + 256;            // [4][64]
  float* mu_a  = red_s + 512;            // [64]
  float* rs_a  = red_s + 576;            // [64]
  const int g  = lane >> 4;
  const int cl = lane & 15;
  #pragma unroll
  for (int i = 0; i < 2; ++i){
    #pragma unroll
    for (int r = 0; r < 4; ++r){
      const int rowl = wm * 32 + i * 16 + g * 4 + r;
      float s = 0.f, q = 0.f;
      #pragma unroll
      for (int j = 0; j < 4; ++j){
        float v = acc[i][j][r] +
                  bf2f(Res[(size_t)(rowA0 + rowl) * 256 + wn * 64 + j * 16 + cl]);
        acc[i][j][r] = v;
        s += v; q += v * v;
      }
      #pragma unroll
      for (int off = 1; off < 16; off <<= 1){
        s += __shfl_xor(s, off); q += __shfl_xor(q, off);
      }
      if (cl == 0){ red_s[wn * 64 + rowl] = s; red_q[wn * 64 + rowl] = q; }
    }
  }
  __syncthreads();
  if (tid < 64){
    float S = red_s[tid] + red_s[64 + tid] + red_s[128 + tid] + red_s[192 + tid];
    float Q = red_q[tid] + red_q[64 + tid] + red_q[128 + tid] + red_q[192 + tid];
    float mu = S * (1.f / 256.f);
    float var = Q * (1.f / 256.f) - mu * mu;
    mu_a[tid] = mu;
    rs_a[tid] = rsqrtf(var + 1e-5f);
  }
  __syncthreads();
  #pragma unroll
  for (int i = 0; i < 2; ++i){
    #pragma unroll
    for (int r = 0; r < 4; ++r){
      const int rowl = wm * 32 + i * 16 + g * 4 + r;
      const float mu = mu_a[rowl], rs = rs_a[rowl];
      #pragma unroll
      for (int j = 0; j < 4; ++j){
        float w = (acc[i][j][r] - mu) * rs;
        size_t idx = (size_t)(rowA0 + rowl) * 256 + wn * 64 + j * 16 + cl;
        if (OUTF32) ((float*)Out)[idx] = w;
        else        ((unsigned short*)Out)[idx] = f2bf(w);
      }
    }
  }
}

// ---------------------------------------------------------------------------
// rsa attention (round-2 verbatim): 4 tokens, 8 heads; separate Q/K/V.
// ---------------------------------------------------------------------------
__global__ __launch_bounds__(256) void attn4_kernel(
    const unsigned short* __restrict__ Q, const unsigned short* __restrict__ K,
    const unsigned short* __restrict__ V, unsigned short* __restrict__ ctx)
{
  const int t = threadIdx.x;
  const int lb = t >> 5, u = t & 31, h = u >> 2, q = u & 3;
  const size_t b = (size_t)blockIdx.x * 8 + lb;
  const size_t base = b * 1024 + h * 32;

  float qf[32];
  {
    const ushort8* qp = (const ushort8*)(Q + base + q * 256);
    #pragma unroll
    for (int g = 0; g < 4; ++g){
      ushort8 v = qp[g];
      #pragma unroll
      for (int e = 0; e < 8; ++e) qf[g * 8 + e] = bf2f(v[e]);
    }
  }
  float sc[4];
  #pragma unroll
  for (int s = 0; s < 4; ++s){
    const ushort8* kp = (const ushort8*)(K + base + s * 256);
    float a0 = 0, a1 = 0, a2 = 0, a3 = 0;
    #pragma unroll
    for (int g = 0; g < 4; ++g){
      ushort8 v = kp[g];
      a0 += qf[g*8+0]*bf2f(v[0]); a1 += qf[g*8+1]*bf2f(v[1]);
      a2 += qf[g*8+2]*bf2f(v[2]); a3 += qf[g*8+3]*bf2f(v[3]);
      a0 += qf[g*8+4]*bf2f(v[4]); a1 += qf[g*8+5]*bf2f(v[5]);
      a2 += qf[g*8+6]*bf2f(v[6]); a3 += qf[g*8+7]*bf2f(v[7]);
    }
    sc[s] = ((a0 + a1) + (a2 + a3)) * 0.17677669529663687f;
  }
  float m = fmaxf(fmaxf(sc[0], sc[1]), fmaxf(sc[2], sc[3]));
  float sum = 0.f;
  #pragma unroll
  for (int s = 0; s < 4; ++s){ sc[s] = __expf(sc[s] - m); sum += sc[s]; }
  float inv = 1.f / sum;

  float o[32];
  #pragma unroll
  for (int d = 0; d < 32; ++d) o[d] = 0.f;
  #pragma unroll
  for (int s = 0; s < 4; ++s){
    float p = sc[s] * inv;
    const ushort8* vp = (const ushort8*)(V + base + s * 256);
    #pragma unroll
    for (int g = 0; g < 4; ++g){
      ushort8 v = vp[g];
      #pragma unroll
      for (int e = 0; e < 8; ++e) o[g * 8 + e] += p * bf2f(v[e]);
    }
  }
  unsigned short* cp = ctx + base + q * 256;
  #pragma unroll
  for (int g = 0; g < 4; ++g){
    ushort8 w;
    #pragma unroll
    for (int e = 0; e < 8; ++e) w[e] = f2bf(o[g * 8 + e]);
    ((ushort8*)cp)[g] = w;
  }
}

// ---------------------------------------------------------------------------
// scatter: x2[b,c,:] = x[b,c,:] + ref[b, rid[c], :]   (bf16 out)
// ---------------------------------------------------------------------------
__global__ __launch_bounds__(256) void scatter_kernel(
    const float* __restrict__ x, const unsigned short* __restrict__ ref,
    unsigned short* __restrict__ x2)
{
  const int b = blockIdx.x, d = threadIdx.x;
  float rv[4];
  #pragma unroll
  for (int r = 0; r < 4; ++r) rv[r] = bf2f(ref[(size_t)b * 1024 + r * 256 + d]);
  const float* xb = x + (size_t)b * 4864 + d;
  unsigned short* xo = x2 + (size_t)b * 4864 + d;
  const int rid[19] = {0,0,1,2,3,0,3,3,0,0,0,1,2,3,0,3,3,1,2};
  #pragma unroll
  for (int c = 0; c < 19; ++c) xo[c * 256] = f2bf(xb[c * 256] + rv[rid[c]]);
}

// ---------------------------------------------------------------------------
// lsa attention (round-2 structure, VECTORIZED staging): 19 tokens, 8 heads.
// One block/batch; K,V fp32 flat in LDS (layout identical to round-2);
// staging now ushort8 (16B/lane coalesced) instead of scalar 2B/lane;
// Q-load hoisted above the barrier to overlap staging latency.
// ---------------------------------------------------------------------------
__global__ __launch_bounds__(256) void attn19_kernel(
    const unsigned short* __restrict__ Q, const unsigned short* __restrict__ K,
    const unsigned short* __restrict__ V, unsigned short* __restrict__ ctx)
{
  __shared__ float Kl[4864];
  __shared__ float Vl[4864];
  const size_t b = blockIdx.x;
  const unsigned short* Kb = K + b * 4864;
  const unsigned short* Vb = V + b * 4864;
  const int t = threadIdx.x;
  const int h = t / 19, qq = t - h * 19;     // valid for t < 152

  // hoisted Q load (global latency overlaps staging)
  float qf[32];
  if (t < 152){
    const ushort8* qp = (const ushort8*)(Q + b * 4864 + qq * 256 + h * 32);
    #pragma unroll
    for (int g = 0; g < 4; ++g){
      ushort8 v = qp[g];
      #pragma unroll
      for (int e = 0; e < 8; ++e) qf[g * 8 + e] = bf2f(v[e]);
    }
  }

  // vectorized staging: 1216 chunks of 8 bf16 -> 8 fp32
  for (int c = t; c < 1216; c += 256){
    int m = (c >= 608);
    int i = c - (m ? 608 : 0);
    ushort8 w = *(const ushort8*)((m ? Vb : Kb) + (size_t)i * 8);
    float* dst = (m ? Vl : Kl) + i * 8;
    #pragma unroll
    for (int e = 0; e < 8; ++e) dst[e] = bf2f(w[e]);
  }
  __syncthreads();
  if (t >= 152) return;

  float p[19];
  float m = -1e30f;
  #pragma unroll
  for (int s = 0; s < 19; ++s){
    const float* kr = &Kl[s * 256 + h * 32];
    float a0 = 0, a1 = 0, a2 = 0, a3 = 0;
    #pragma unroll
    for (int d = 0; d < 32; d += 4){
      a0 += qf[d+0] * kr[d+0]; a1 += qf[d+1] * kr[d+1];
      a2 += qf[d+2] * kr[d+2]; a3 += qf[d+3] * kr[d+3];
    }
    p[s] = ((a0 + a1) + (a2 + a3)) * 0.17677669529663687f;
    m = fmaxf(m, p[s]);
  }
  float sum = 0.f;
  #pragma unroll
  for (int s = 0; s < 19; ++s){ p[s] = __expf(p[s] - m); sum += p[s]; }
  float inv = 1.f / sum;

  float o[32];
  #pragma unroll
  for (int d = 0; d < 32; ++d) o[d] = 0.f;
  #pragma unroll
  for (int s = 0; s < 19; ++s){
    float ps = p[s] * inv;
    const float* vr = &Vl[s * 256 + h * 32];
    #pragma unroll
    for (int d = 0; d < 32; ++d) o[d] += ps * vr[d];
  }
  unsigned short* cp = ctx + b * 4864 + qq * 256 + h * 32;
  #pragma unroll
  for (int g = 0; g < 4; ++g){
    ushort8 w;
    #pragma unroll
    for (int e = 0; e < 8; ++e) w[e] = f2bf(o[g * 8 + e]);
    ((ushort8*)cp)[g] = w;
  }
}

// ============================================================================
extern "C" void kernel_launch(void* const* d_in, const int* in_sizes, int n_in,
                              void* d_out, int out_size, void* d_ws, size_t ws_size,
                              hipStream_t stream)
{
  (void)n_in; (void)out_size;
  const float* x  = (const float*)d_in[0];
  const float* rq = (const float*)d_in[1];
  const float* rk = (const float*)d_in[2];
  const float* rv = (const float*)d_in[3];
  const float* ro = (const float*)d_in[4];
  const float* lq = (const float*)d_in[5];
  const float* lk = (const float*)d_in[6];
  const float* lv = (const float*)d_in[7];
  const float* lo = (const float*)d_in[8];
  const float* w1 = (const float*)d_in[9];
  const float* w2 = (const float*)d_in[10];

  const int B = in_sizes[0] / 4864;          // 4096
  const int M4  = B * 4;                     // 16384
  const int M19 = B * 19;                    // 77824
  const int MH  = M19 / 2;                   // 38912
  const size_t MB = 1ull << 20;
  if (ws_size < 240 * MB) return;

  char* ws = (char*)d_ws;
  unsigned short* WT    = (unsigned short*)(ws);
  unsigned short* FE    = (unsigned short*)(ws + 2   * MB);
  unsigned short* Q4    = (unsigned short*)(ws + 10  * MB);
  unsigned short* K4    = (unsigned short*)(ws + 18  * MB);
  unsigned short* V4    = (unsigned short*)(ws + 26  * MB);
  unsigned short* CTX4  = (unsigned short*)(ws + 34  * MB);
  unsigned short* REF   = (unsigned short*)(ws + 42  * MB);
  unsigned short* X2    = (unsigned short*)(ws + 50  * MB);
  unsigned short* Q19   = (unsigned short*)(ws + 88  * MB);
  unsigned short* K19   = (unsigned short*)(ws + 126 * MB);
  unsigned short* V19   = (unsigned short*)(ws + 164 * MB);
  unsigned short* CTX19 = (unsigned short*)(ws + 202 * MB);
  unsigned short* FUSED = (unsigned short*)(ws + 88  * MB);  // alias Q19 (dead)
  unsigned short* H     = (unsigned short*)(ws + 126 * MB);  // alias K19+V19 (dead)
  float* out = (float*)d_out;

  // 1. weights -> bf16 [n][k]
  wprep_all<<<4096, 256, 0, stream>>>(rq, rk, rv, ro, lq, lk, lv, lo, w1, w2, WT);
  // 2. region pool
  pool_kernel<<<B, 256, 0, stream>>>(x, FE);
  // 3. rsa QKV (one pass, split epilogue; 6*128 grid, %8==0)
  gemm_kernel<0,1,6><<<6 * (M4/128), 256, 0, stream>>>(FE, WT, Q4, K4, V4, M4, 768, 256);
  // 4. rsa attention
  attn4_kernel<<<B/8, 256, 0, stream>>>(Q4, K4, V4, CTX4);
  // 5. rsa out-proj + LN(.. + fe) -> REF
  gemm_ln_kernel<0><<<M4/64, 512, 0, stream>>>(CTX4, WT + 3*65536, FE, REF, M4, 256);
  // 6. x2 = x + ref[rid]
  scatter_kernel<<<B, 256, 0, stream>>>(x, REF, X2);
  // 7. lsa QKV (one pass, split epilogue; 6*608 grid, %8==0)
  gemm_kernel<0,1,6><<<6 * (M19/128), 256, 0, stream>>>(X2, WT + 4*65536, Q19, K19, V19, M19, 768, 256);
  // 8. lsa attention
  attn19_kernel<<<B, 256, 0, stream>>>(Q19, K19, V19, CTX19);
  // 9. lsa out-proj + LN(.. + x2) -> FUSED   (Q19 dead)
  gemm_ln_kernel<0><<<M19/64, 512, 0, stream>>>(CTX19, WT + 7*65536, X2, FUSED, M19, 256);
  // 10. FFN halves: H = relu(FUSED @ w1); out = LN(H @ w2 + FUSED)
  for (int hf = 0; hf < 2; ++hf){
    const unsigned short* Fh = FUSED + (size_t)hf * MH * 256;
    gemm_kernel<1,0,8><<<8 * (MH/128), 256, 0, stream>>>(Fh, WT + 524288, H, nullptr, nullptr, MH, 1024, 256);
    gemm_ln_kernel<1><<<MH/64, 512, 0, stream>>>(H, WT + 786432, Fh,
                                                 out + (size_t)hf * MH * 256, MH, 1024);
  }
}